// Round 4
// baseline (487.530 us; speedup 1.0000x reference)
//
#include <hip/hip_runtime.h>

#define B_ 4
#define S_ 2048
#define D_ 1024
#define M_ (B_*S_)           // 8192
#define K2_ 2048
#define N2_ 2048
#define NTOT (B_*S_*D_)      // 8388608
#define DD (D_*D_)           // 1048576

typedef __attribute__((ext_vector_type(4))) float f32x4;
typedef __attribute__((ext_vector_type(8))) short short8;
typedef __attribute__((ext_vector_type(4))) unsigned short u16x4;
typedef __attribute__((ext_vector_type(8))) unsigned short u16x8;

static __device__ __forceinline__ unsigned short f2bf(float f) {
    union { float f; unsigned int u; } v; v.f = f;
    unsigned int u = v.u;
    unsigned int r = (u + 0x7fffu + ((u >> 16) & 1u)) >> 16;
    return (unsigned short)r;
}
static __device__ __forceinline__ float bf2f(unsigned short h) {
    union { unsigned int u; float f; } v; v.u = ((unsigned int)h) << 16;
    return v.f;
}

// scal layout (fp32 slots): [0..1] sumsq[l], [2..9] diff2[l*4+b],
// [10..17] prev2[l*4+b], [18..25] diag-max bits, [26..33] diag-min bits,
// [64..2111] dampv[2][1024]

// ---------------------------------------------------------------------------
// gemm_main2: paired-tile mixing GEMM (905 TF verified r3). Block (nt, mt)
// computes real+imag column tiles against one A tile. Emits bd2, raw |bd|
// transposed into magT[b][d][s], and sum(bd^2).
// ---------------------------------------------------------------------------
__global__ __launch_bounds__(256, 2) void gemm_main2(const unsigned short* __restrict__ A2,
                                                     const unsigned short* __restrict__ B2T,
                                                     unsigned short* __restrict__ bd2,
                                                     unsigned short* __restrict__ magT,
                                                     float* __restrict__ scal, int l)
{
    __shared__ unsigned short smem[3 * 128 * 64];   // 48 KB: As | Bsr | Bsi
    __shared__ float red[4];
    unsigned short* As  = smem;
    unsigned short* Bsr = smem + 8192;
    unsigned short* Bsi = smem + 16384;

    f32x4 accr[4][4], acci[4][4];
#pragma unroll
    for (int i = 0; i < 4; ++i)
#pragma unroll
        for (int j = 0; j < 4; ++j) { accr[i][j] = (f32x4)0.0f; acci[i][j] = (f32x4)0.0f; }

    const int nt = blockIdx.x, mt = blockIdx.y;
    const int tid = threadIdx.x, wave = tid >> 6, lane = tid & 63;
    const int q = lane >> 4, lm = lane & 15;
    const int wm = (wave >> 1) * 64, wn = (wave & 1) * 64;
    const int crow = lane >> 3;
    const int gcol = ((lane & 7) ^ crow) * 8;

    const unsigned short* Ag  = A2  + (long)mt * 128 * K2_;
    const unsigned short* Bgr = B2T + (long)(nt * 128) * K2_;
    const unsigned short* Bgi = B2T + (long)(nt * 128 + 1024) * K2_;

    for (int kt = 0; kt < K2_ / 64; ++kt) {
        const long k0 = (long)kt * 64;
        __syncthreads();
#pragma unroll
        for (int i2 = 0; i2 < 4; ++i2) {
            int c   = i2 * 4 + wave;
            int row = c * 8 + crow;
            long go = (long)row * K2_ + k0 + gcol;
            __builtin_amdgcn_global_load_lds((const __attribute__((address_space(1))) void*)(Ag + go),
                                             (__attribute__((address_space(3))) void*)(As + c * 512), 16, 0, 0);
            __builtin_amdgcn_global_load_lds((const __attribute__((address_space(1))) void*)(Bgr + go),
                                             (__attribute__((address_space(3))) void*)(Bsr + c * 512), 16, 0, 0);
            __builtin_amdgcn_global_load_lds((const __attribute__((address_space(1))) void*)(Bgi + go),
                                             (__attribute__((address_space(3))) void*)(Bsi + c * 512), 16, 0, 0);
        }
        __syncthreads();
#pragma unroll
        for (int kk = 0; kk < 64; kk += 32) {
            short8 a[4], br[4], bi[4];
#pragma unroll
            for (int t = 0; t < 4; ++t) {
                int arow  = wm + t * 16 + lm;
                int aslot = ((kk >> 3) + q) ^ (arow & 7);
                a[t] = *(const short8*)(As + arow * 64 + aslot * 8);
                int brow  = wn + t * 16 + lm;
                int bslot = ((kk >> 3) + q) ^ (brow & 7);
                br[t] = *(const short8*)(Bsr + brow * 64 + bslot * 8);
                bi[t] = *(const short8*)(Bsi + brow * 64 + bslot * 8);
            }
#pragma unroll
            for (int um = 0; um < 4; ++um)
#pragma unroll
                for (int un = 0; un < 4; ++un) {
                    accr[um][un] = __builtin_amdgcn_mfma_f32_16x16x32_bf16(a[um], br[un], accr[um][un], 0, 0, 0);
                    acci[um][un] = __builtin_amdgcn_mfma_f32_16x16x32_bf16(a[um], bi[un], acci[um][un], 0, 0, 0);
                }
        }
    }

    __syncthreads();
    unsigned short* magLds = smem;       // [128 d][136 stride] bf16
    float ss = 0.f;
#pragma unroll
    for (int um = 0; um < 4; ++um) {
#pragma unroll
        for (int un = 0; un < 4; ++un) {
            int colb = wn + un * 16 + lm;
            int coln = nt * 128 + colb;
            u16x4 magv;
#pragma unroll
            for (int i = 0; i < 4; ++i) {
                long rowm = (long)mt * 128 + wm + um * 16 + q * 4 + i;
                float vr = accr[um][un][i];
                float vi = acci[um][un][i];
                bd2[rowm * N2_ + coln]        = f2bf(vr);
                bd2[rowm * N2_ + 1024 + coln] = f2bf(vi);
                float s2 = vr * vr + vi * vi;
                ss += s2;
                magv[i] = f2bf(sqrtf(s2));
            }
            *(u16x4*)(magLds + colb * 136 + wm + um * 16 + q * 4) = magv;
        }
    }
    for (int off = 32; off > 0; off >>= 1) ss += __shfl_down(ss, off);
    if (lane == 0) red[wave] = ss;
    __syncthreads();
    if (tid == 0) atomicAdd(scal + l, red[0] + red[1] + red[2] + red[3]);

    const int b   = mt >> 4;
    const long s0 = (long)(mt & 15) * 128;
#pragma unroll
    for (int it = 0; it < 8; ++it) {
        int sid = it * 256 + tid;
        int row = sid >> 4, seg = sid & 15;
        unsigned short* dst = magT + (long)b * D_ * S_ + (long)(nt * 128 + row) * S_ + s0 + seg * 8;
        *(u16x8*)dst = *(const u16x8*)(magLds + row * 136 + seg * 8);
    }
}

// 128x128 MFMA core (XOR-swizzled LDS), generic strides/kiters
__device__ __forceinline__ void mfma_gemm_128(const unsigned short* __restrict__ Ag, long astride,
                                              const unsigned short* __restrict__ Bg, long bstride,
                                              int kiters,
                                              unsigned short* As, unsigned short* Bs,
                                              f32x4 acc[4][4])
{
    const int tid  = threadIdx.x;
    const int wave = tid >> 6, lane = tid & 63;
    const int q    = lane >> 4, lm = lane & 15;
    const int wm   = (wave >> 1) * 64, wn = (wave & 1) * 64;
    const int crow = lane >> 3;
    const int gcol = ((lane & 7) ^ crow) * 8;

    for (int kt = 0; kt < kiters; ++kt) {
        const long k0 = (long)kt * 64;
        __syncthreads();
#pragma unroll
        for (int i2 = 0; i2 < 4; ++i2) {
            int c   = i2 * 4 + wave;
            int row = c * 8 + crow;
            const unsigned short* ga = Ag + (long)row * astride + k0 + gcol;
            const unsigned short* gb = Bg + (long)row * bstride + k0 + gcol;
            __builtin_amdgcn_global_load_lds((const __attribute__((address_space(1))) void*)ga,
                                             (__attribute__((address_space(3))) void*)(As + c * 512), 16, 0, 0);
            __builtin_amdgcn_global_load_lds((const __attribute__((address_space(1))) void*)gb,
                                             (__attribute__((address_space(3))) void*)(Bs + c * 512), 16, 0, 0);
        }
        __syncthreads();
#pragma unroll
        for (int kk = 0; kk < 64; kk += 32) {
            short8 a[4], b[4];
#pragma unroll
            for (int t = 0; t < 4; ++t) {
                int arow  = wm + t * 16 + lm;
                int aslot = ((kk >> 3) + q) ^ (arow & 7);
                a[t] = *(const short8*)(As + arow * 64 + aslot * 8);
                int brow  = wn + t * 16 + lm;
                int bslot = ((kk >> 3) + q) ^ (brow & 7);
                b[t] = *(const short8*)(Bs + brow * 64 + bslot * 8);
            }
#pragma unroll
            for (int um = 0; um < 4; ++um)
#pragma unroll
                for (int un = 0; un < 4; ++un)
                    acc[um][un] = __builtin_amdgcn_mfma_f32_16x16x32_bf16(a[um], b[un], acc[um][un], 0, 0, 0);
        }
    }
}

// ---------------------------------------------------------------------------
// gemmH_split: Gram partials with the 128-tile core. grid(36 pairs, B, 4 kc);
// each block does K=512 and stores a raw 128x128 fp32 partial tile to pbuf.
// ---------------------------------------------------------------------------
__global__ __launch_bounds__(256, 2) void gemmH_split(const unsigned short* __restrict__ magT,
                                                      float* __restrict__ pbuf)
{
    __shared__ unsigned short As[128 * 64];
    __shared__ unsigned short Bs[128 * 64];
    f32x4 acc[4][4];
#pragma unroll
    for (int i = 0; i < 4; ++i)
#pragma unroll
        for (int j = 0; j < 4; ++j) acc[i][j] = (f32x4)0.0f;

    const int pair = blockIdx.x, b = blockIdx.y, kc = blockIdx.z;
    int idx = pair, ty = 0;
    while (idx >= 8 - ty) { idx -= 8 - ty; ++ty; }
    const int tx = ty + idx;                 // tx >= ty (128-row tiles)

    const unsigned short* Mb = magT + (long)b * D_ * S_ + (long)kc * 512;
    mfma_gemm_128(Mb + (long)ty * 128 * S_, S_,
                  Mb + (long)tx * 128 * S_, S_, 8, As, Bs, acc);

    float* pt = pbuf + ((long)(kc * 36 + pair) * B_ + b) * 16384;
    const int tid = threadIdx.x, wave = tid >> 6, lane = tid & 63;
    const int q = lane >> 4, lm = lane & 15;
    const int wm = (wave >> 1) * 64, wn = (wave & 1) * 64;
#pragma unroll
    for (int um = 0; um < 4; ++um)
#pragma unroll
        for (int un = 0; un < 4; ++un) {
            int c = wn + un * 16 + lm;
#pragma unroll
            for (int i = 0; i < 4; ++i) {
                int r = wm + um * 16 + q * 4 + i;
                pt[r * 128 + c] = acc[um][un][i];
            }
        }
}

// ---------------------------------------------------------------------------
// reduce_H: sum 4 partials, scale by damp[r]*damp[c]/(rms^2*S); fused
// ||H-Hp||^2, ||Hp||^2, diag min/max. Stores H upper tiles only (l==0).
// l==0: Hp asymmetric -> read both (r,c),(c,r). l==1: Hp=H0 symmetric,
// upper tiles only -> double-count off-diag tiles.
// ---------------------------------------------------------------------------
__global__ __launch_bounds__(256) void reduce_H(const float* __restrict__ pbuf,
                                                const float* __restrict__ Hp,
                                                float* __restrict__ H,
                                                float* __restrict__ scal,
                                                const float* __restrict__ dampv, int l)
{
    __shared__ float redd[4], redp[4];
    const int pair = blockIdx.x, b = blockIdx.y;
    int idx0 = pair, ty = 0;
    while (idx0 >= 8 - ty) { idx0 -= 8 - ty; ++ty; }
    const int tx = ty + idx0;
    const int diag_tile = (tx == ty);

    float mean = fmaxf(scal[l] / (float)NTOT, 1e-12f);
    float inv  = 1.0f / fmaxf(sqrtf(mean), 1e-3f);
    const float scale = inv * inv / (float)S_;

    const int tid = threadIdx.x;
    float d2 = 0.f, p2 = 0.f;
    float dmx = 0.f, dmn = 3.402823466e38f;
    for (int it = 0; it < 64; ++it) {
        int idx = it * 256 + tid;
        int r = idx >> 7, c = idx & 127;
        int gr = ty * 128 + r, gc = tx * 128 + c;
        float s = pbuf[((long)(0 * 36 + pair) * B_ + b) * 16384 + idx]
                + pbuf[((long)(1 * 36 + pair) * B_ + b) * 16384 + idx]
                + pbuf[((long)(2 * 36 + pair) * B_ + b) * 16384 + idx]
                + pbuf[((long)(3 * 36 + pair) * B_ + b) * 16384 + idx];
        float h = s * scale * dampv[gr] * dampv[gc];
        long adr = (long)b * DD + (long)gr * D_ + gc;
        if (l == 0) {
            float hp1 = Hp[adr];
            H[adr] = h;
            float df1 = h - hp1;
            if (diag_tile) {
                d2 += df1 * df1; p2 += hp1 * hp1;
            } else {
                float hp2 = Hp[(long)b * DD + (long)gc * D_ + gr];
                float df2 = h - hp2;
                d2 += df1 * df1 + df2 * df2;
                p2 += hp1 * hp1 + hp2 * hp2;
            }
        } else {
            float hp1 = Hp[adr];
            float df1 = h - hp1;
            float w = diag_tile ? 1.0f : 2.0f;
            d2 += w * df1 * df1;
            p2 += w * hp1 * hp1;
        }
        if (diag_tile && gr == gc) { dmx = fmaxf(dmx, h); dmn = fminf(dmn, h); }
    }
    int lane = tid & 63, wave = tid >> 6;
    for (int off = 32; off > 0; off >>= 1) { d2 += __shfl_down(d2, off); p2 += __shfl_down(p2, off); }
    if (lane == 0) { redd[wave] = d2; redp[wave] = p2; }
    if (diag_tile) {
        atomicMax((int*)scal + 18 + l * 4 + b, __float_as_int(dmx));
        atomicMin((int*)scal + 26 + l * 4 + b, __float_as_int(dmn));
    }
    __syncthreads();
    if (tid == 0) {
        atomicAdd(scal + 2 + l * 4 + b,  redd[0] + redd[1] + redd[2] + redd[3]);
        atomicAdd(scal + 10 + l * 4 + b, redp[0] + redp[1] + redp[2] + redp[3]);
    }
}

// A2 <- bf16 pack of x; block 0 inits scalars. (No fp32 psi write.)
__global__ void init_kernel(const float* __restrict__ xr, const float* __restrict__ xi,
                            unsigned short* __restrict__ A2, float* __restrict__ scal)
{
    if (blockIdx.x == 0 && threadIdx.x < 34)
        scal[threadIdx.x] = (threadIdx.x >= 26) ? 3.402823466e38f : 0.0f;
    long t = (long)blockIdx.x * 256 + threadIdx.x;
    long i = t * 4;
    f32x4 r  = *(const f32x4*)(xr + i);
    f32x4 im = *(const f32x4*)(xi + i);
    long m = i / D_; int d = (int)(i % D_);
    u16x4 rr, ii;
#pragma unroll
    for (int j = 0; j < 4; ++j) { rr[j] = f2bf(r[j]); ii[j] = f2bf(im[j]); }
    *(u16x4*)(A2 + m * K2_ + d) = rr;
    *(u16x4*)(A2 + m * K2_ + D_ + d) = ii;
}

// B2T[n][k] = (B2 - I)[k][n] for layer l
__global__ __launch_bounds__(256) void pack_b2t(const float* __restrict__ Wr_all,
                                                const float* __restrict__ Wi_all,
                                                unsigned short* __restrict__ B2T, int l)
{
    __shared__ float T[64][65];
    const float* Wr = Wr_all + (long)l * DD;
    const float* Wi = Wi_all + (long)l * DD;
    int k0 = blockIdx.x * 64;
    int n0 = blockIdx.y * 64;
    int t = threadIdx.x;
#pragma unroll
    for (int it = 0; it < 16; ++it) {
        int idx = it * 256 + t;
        int kl = idx >> 6, nl = idx & 63;
        int k = k0 + kl, n = n0 + nl;
        float v;
        if (k < D_) v = (n < D_) ? Wr[k * D_ + n] : Wi[k * D_ + (n - D_)];
        else        v = (n < D_) ? -Wi[(k - D_) * D_ + n] : Wr[(k - D_) * D_ + (n - D_)];
        if (k == n) v -= 1.0f;
        T[kl][nl] = v;
    }
    __syncthreads();
#pragma unroll
    for (int it = 0; it < 16; ++it) {
        int idx = it * 256 + t;
        int nl = idx >> 6, kl = idx & 63;
        B2T[(long)(n0 + nl) * K2_ + (k0 + kl)] = f2bf(T[kl][nl]);
    }
}

__global__ void damp_kernel(const float* __restrict__ Lops, float* __restrict__ dampv)
{
    int g = blockIdx.x;
    int l = g >> 2;
    int d = (g & 3) * 256 + threadIdx.x;
    const float* Lp = Lops + (long)l * 4 * D_;
    float s = 0.f;
#pragma unroll
    for (int k = 0; k < 4; ++k) { float v = Lp[k * D_ + d]; s += v * v; }
    dampv[l * D_ + d] = 1.0f - 0.01f * s;
}

// psi_dst = src + bd*damp*factor (complex); factors from scalars; opt A2 repack
__global__ void update_kernel(const unsigned short* __restrict__ bd2,
                              const float* __restrict__ dampv,
                              const float* __restrict__ scal,
                              const float* __restrict__ theta,
                              const float* __restrict__ jscale,
                              const float* __restrict__ kappa, int l,
                              const float* __restrict__ src_r,
                              const float* __restrict__ src_i,
                              float* __restrict__ dst_r,
                              float* __restrict__ dst_i,
                              unsigned short* __restrict__ A2,
                              int write_a2)
{
    long t = (long)blockIdx.x * 256 + threadIdx.x;
    long i = t * 4;
    long m = i / D_; int d = (int)(i % D_);
    int b = (int)(m >> 11);

    float dn = sqrtf(scal[2 + l * 4 + b]);
    float pn = sqrtf(scal[10 + l * 4 + b]);
    float K  = dn / (pn + 1e-6f);
    float mx = __int_as_float(((const int*)scal)[18 + l * 4 + b]);
    float mn = __int_as_float(((const int*)scal)[26 + l * 4 + b]);
    int jumped  = K > kappa[l];
    int escaped = (mx / (mn + 1e-12f)) > 100.0f;
    float js = jumped ? jscale[l] : 1.0f;
    float th = theta[l];
    float fr = js * (escaped ? cosf(th) : 1.0f);
    float fi = js * (escaped ? sinf(th) : 0.0f);

    u16x4 brv = *(const u16x4*)(bd2 + m * N2_ + d);
    u16x4 biv = *(const u16x4*)(bd2 + m * N2_ + D_ + d);
    f32x4 w  = *(const f32x4*)(dampv + d);
    f32x4 pr = *(const f32x4*)(src_r + i);
    f32x4 pi = *(const f32x4*)(src_i + i);
    u16x4 ar, ai;
#pragma unroll
    for (int j = 0; j < 4; ++j) {
        float br = bf2f(brv[j]) * w[j];
        float bi = bf2f(biv[j]) * w[j];
        float nr = pr[j] + br * fr - bi * fi;
        float ni = pi[j] + br * fi + bi * fr;
        pr[j] = nr; pi[j] = ni;
        ar[j] = f2bf(nr); ai[j] = f2bf(ni);
    }
    *(f32x4*)(dst_r + i) = pr;
    *(f32x4*)(dst_i + i) = pi;
    if (write_a2) {
        *(u16x4*)(A2 + m * K2_ + d) = ar;
        *(u16x4*)(A2 + m * K2_ + D_ + d) = ai;
    }
}

extern "C" void kernel_launch(void* const* d_in, const int* in_sizes, int n_in,
                              void* d_out, int out_size, void* d_ws, size_t ws_size,
                              hipStream_t stream)
{
    const float* xr     = (const float*)d_in[0];
    const float* xi     = (const float*)d_in[1];
    const float* Hprev  = (const float*)d_in[2];
    const float* Wr     = (const float*)d_in[3];
    const float* Wi     = (const float*)d_in[4];
    const float* Lops   = (const float*)d_in[5];
    const float* theta  = (const float*)d_in[6];
    const float* jscale = (const float*)d_in[7];
    const float* kappa  = (const float*)d_in[8];

    float* psi_r = (float*)d_out;           // [B,S,D] real plane
    float* psi_i = psi_r + NTOT;            // imag plane

    char* ws = (char*)d_ws;
    unsigned short* A2   = (unsigned short*)ws;               // 32 MiB
    float* pbuf          = (float*)ws;                        // 36.9 MiB, aliases A2+B2T
                                                              // (both dead during H phase)
    unsigned short* B2T  = (unsigned short*)(ws + 33554432);  //  8 MiB (per-layer)
    unsigned short* bd2  = (unsigned short*)(ws + 41943040);  // 32 MiB
    unsigned short* magT = (unsigned short*)(ws + 75497472);  // 16 MiB
    float* H             = (float*)(ws + 92274688);           // 16 MiB (upper tiles, H0 only)
    float* scal          = (float*)(ws + 109051904);          // scalars + dampv
    float* dampv         = scal + 64;                         // [2][1024]

    init_kernel<<<NTOT / 4 / 256, 256, 0, stream>>>(xr, xi, A2, scal);
    damp_kernel<<<8, 256, 0, stream>>>(Lops, dampv);

    for (int l = 0; l < 2; ++l) {
        pack_b2t<<<dim3(32, 32), 256, 0, stream>>>(Wr, Wi, B2T, l);
        gemm_main2<<<dim3(8, M_ / 128), 256, 0, stream>>>(A2, B2T, bd2, magT, scal, l);
        gemmH_split<<<dim3(36, B_, 4), 256, 0, stream>>>(magT, pbuf);
        reduce_H<<<dim3(36, B_), 256, 0, stream>>>(
            pbuf, (l == 0) ? Hprev : H, H, scal, dampv + l * D_, l);
        update_kernel<<<NTOT / 4 / 256, 256, 0, stream>>>(
            bd2, dampv + l * D_, scal, theta, jscale, kappa, l,
            (l == 0) ? xr : psi_r, (l == 0) ? xi : psi_i,
            psi_r, psi_i, A2, l == 0);
    }
}